// Round 15
// baseline (250.102 us; speedup 1.0000x reference)
//
#include <hip/hip_runtime.h>
#include <math.h>

#define TT 100
#define PP 1000
#define NJ 52      // padded j count (50 real)
#define GROW 56    // G row stride floats (224B, 16B aligned; 14 float4)
#define NBLK 64

typedef _Float16 half2v __attribute__((ext_vector_type(2)));

__device__ __forceinline__ half2v as_h2(float f) {
    union { float x; half2v h; } u; u.x = f; return u.h;
}

// ws layout (floats):
//   xk : [800][256] at 0        (204800)
//   XcT: [56][1000] at 204800   (56000)
//   G  : [800][56]  at 260800   (44800)
//   bar: 2 ints     at 305600   (zeroed via hipMemsetAsync before each launch)

// Manual grid barrier. Safe per capacity arithmetic: 64 blocks, launch_bounds
// (256,1) -> 1 block/CU, 256 CUs -> all 64 co-resident at dispatch. Counters
// are single-use per launch (re-zeroed by the stream memset each call).
// R14's hipLaunchCooperativeKernel never executed (out stayed zero) -- this
// replaces it with a mechanism whose failure mode is visible.
__device__ __forceinline__ void gbar(int* cnt) {
    __syncthreads();
    __threadfence();
    if (threadIdx.x == 0) {
        __hip_atomic_fetch_add(cnt, 1, __ATOMIC_ACQ_REL, __HIP_MEMORY_SCOPE_AGENT);
        while (__hip_atomic_load(cnt, __ATOMIC_ACQUIRE, __HIP_MEMORY_SCOPE_AGENT) < NBLK) {
            __builtin_amdgcn_s_sleep(8);
        }
    }
    __syncthreads();
    __threadfence();
}

__global__ __launch_bounds__(256, 1) void fused(
    const int* __restrict__ pro_id, const int* __restrict__ label,
    const float* __restrict__ X, const float* __restrict__ cos_X,
    const float* __restrict__ onehot, const float* __restrict__ kern,
    const float* __restrict__ rec, const float* __restrict__ bias,
    const float* __restrict__ W1, const float* __restrict__ b1,
    const float* __restrict__ W2, const float* __restrict__ b2,
    float* __restrict__ xk, float* __restrict__ XcT,
    float* __restrict__ G, float* __restrict__ out, int* __restrict__ bar)
{
    __shared__ __align__(16) float smem[14720];  // 58.9 KB union (all phases)
    const int tid = threadIdx.x;
    const int bid = blockIdx.x;

    // ================= PHASE A: xk[row][j] = bias[j] + sum_k xt[row][k]*kern[k][j] =====
    {
        const int r0 = bid * 13;
        if (r0 < 800) {
            float (*xt)[256] = (float(*)[256])smem;   // 13x256 = 13.3 KB
            const int j = tid;
#pragma unroll
            for (int r = 0; r < 13; ++r) {
                int row = r0 + r; int rowc = (row < 800) ? row : 799;
                int pid = pro_id[rowc]; int lab = label[rowc];
                xt[r][j] = X[pid * 128 + (j & 127)] * onehot[lab * 256 + j];
            }
            __syncthreads();
            float acc[13];
            float bj = bias[j];
#pragma unroll
            for (int r = 0; r < 13; ++r) acc[r] = bj;
            float kc[8];
#pragma unroll
            for (int i = 0; i < 8; ++i) kc[i] = kern[i * 256 + j];
            for (int kg = 0; kg < 32; ++kg) {
                float kn[8];
                const int kgn = (kg < 31) ? kg + 1 : 31;
#pragma unroll
                for (int i = 0; i < 8; ++i) kn[i] = kern[(kgn * 8 + i) * 256 + j];
                const int k0 = kg * 8;
#pragma unroll
                for (int r = 0; r < 13; ++r) {
                    float4 x0 = *(const float4*)&xt[r][k0];
                    float4 x1 = *(const float4*)&xt[r][k0 + 4];
                    acc[r] += x0.x * kc[0] + x0.y * kc[1] + x0.z * kc[2] + x0.w * kc[3]
                            + x1.x * kc[4] + x1.y * kc[5] + x1.z * kc[6] + x1.w * kc[7];
                }
#pragma unroll
                for (int i = 0; i < 8; ++i) kc[i] = kn[i];
            }
#pragma unroll
            for (int r = 0; r < 13; ++r) {
                int row = r0 + r;
                if (row < 800) xk[row * 256 + j] = acc[r];
            }
        }
    }

    gbar(&bar[0]);

    // ================= PHASE B: blocks 0..7 LSTM v7 + G tail; 8..23 XcT ================
    if (bid < 8) {
        float* h_all  = smem;            // [100][64] f32 = 25600 B
        float* hwork  = smem + 6400;     // [64] f16 = 128 B
        float* w1s    = smem + 6432;     // [64][52] = 13312 B
        const int b = bid;

        if (tid >= 64) {                 // waves 1..3 stage w1s
            for (int idx = tid - 64; idx < 3200; idx += 192) {
                int u2 = idx / 50, jj = idx - u2 * 50;
                w1s[u2 * 52 + jj] = W1[idx];
            }
        }

        if (tid < 64) {                  // wave 0: the whole recurrence
            const int u = tid;
            half2v rp[4][32];
#pragma unroll
            for (int m = 0; m < 32; ++m) {
#pragma unroll
                for (int g2 = 0; g2 < 4; ++g2) {
                    float r0v = rec[(2 * m) * 256 + g2 * 64 + u];
                    float r1v = rec[(2 * m + 1) * 256 + g2 * 64 + u];
                    half2v pv; pv.x = (_Float16)r0v; pv.y = (_Float16)r1v;
                    rp[g2][m] = pv;
                }
            }
            ((_Float16*)hwork)[u] = (_Float16)0.f;   // h(-1) = 0

            const float* xkb = xk + b * TT * 256;
            float xi0 = xkb[u],             xf0 = xkb[64 + u],
                  xg0 = xkb[128 + u],       xo0 = xkb[192 + u];
            float xi1 = xkb[256 + u],       xf1 = xkb[256 + 64 + u],
                  xg1 = xkb[256 + 128 + u], xo1 = xkb[256 + 192 + u];
            float xi2 = xkb[512 + u],       xf2 = xkb[512 + 64 + u],
                  xg2 = xkb[512 + 128 + u], xo2 = xkb[512 + 192 + u];
            float c = 0.f;

            for (int t = 0; t < TT; ++t) {
                float zi = xi0, zf = xf0, zg = xg0, zo = xo0;
                xi0 = xi1; xf0 = xf1; xg0 = xg1; xo0 = xo1;
                xi1 = xi2; xf1 = xf2; xg1 = xg2; xo1 = xo2;
                int tn = (t + 3 < TT) ? t + 3 : TT - 1;
                const float* xp = xkb + tn * 256;
                xi2 = xp[u]; xf2 = xp[64 + u]; xg2 = xp[128 + u]; xo2 = xp[192 + u];

                const float4* hw4 = (const float4*)hwork;
#pragma unroll
                for (int ch = 0; ch < 8; ++ch) {
                    float4 hv = hw4[ch];
                    half2v p0 = as_h2(hv.x), p1 = as_h2(hv.y),
                           p2 = as_h2(hv.z), p3 = as_h2(hv.w);
                    zi = __builtin_amdgcn_fdot2(p0, rp[0][ch * 4 + 0], zi, false);
                    zf = __builtin_amdgcn_fdot2(p0, rp[1][ch * 4 + 0], zf, false);
                    zg = __builtin_amdgcn_fdot2(p0, rp[2][ch * 4 + 0], zg, false);
                    zo = __builtin_amdgcn_fdot2(p0, rp[3][ch * 4 + 0], zo, false);
                    zi = __builtin_amdgcn_fdot2(p1, rp[0][ch * 4 + 1], zi, false);
                    zf = __builtin_amdgcn_fdot2(p1, rp[1][ch * 4 + 1], zf, false);
                    zg = __builtin_amdgcn_fdot2(p1, rp[2][ch * 4 + 1], zg, false);
                    zo = __builtin_amdgcn_fdot2(p1, rp[3][ch * 4 + 1], zo, false);
                    zi = __builtin_amdgcn_fdot2(p2, rp[0][ch * 4 + 2], zi, false);
                    zf = __builtin_amdgcn_fdot2(p2, rp[1][ch * 4 + 2], zf, false);
                    zg = __builtin_amdgcn_fdot2(p2, rp[2][ch * 4 + 2], zg, false);
                    zo = __builtin_amdgcn_fdot2(p2, rp[3][ch * 4 + 2], zo, false);
                    zi = __builtin_amdgcn_fdot2(p3, rp[0][ch * 4 + 3], zi, false);
                    zf = __builtin_amdgcn_fdot2(p3, rp[1][ch * 4 + 3], zf, false);
                    zg = __builtin_amdgcn_fdot2(p3, rp[2][ch * 4 + 3], zg, false);
                    zo = __builtin_amdgcn_fdot2(p3, rp[3][ch * 4 + 3], zo, false);
                }
                float gi = 1.f / (1.f + __expf(-zi));
                float gf = 1.f / (1.f + __expf(-zf));
                float gg = 2.f / (1.f + __expf(-2.f * zg)) - 1.f;
                float go = 1.f / (1.f + __expf(-zo));
                c = gf * c + gi * gg;
                float h = go * (2.f / (1.f + __expf(-2.f * c)) - 1.f);
                h_all[t * 64 + u] = h;                 // f32 history for tail
                ((_Float16*)hwork)[u] = (_Float16)h;   // f16 row for next step
            }
        }
        __syncthreads();

        // ---- G tail (all 256 threads): G[b*100+row][j] = h(row) . W1[:,j] ----
        const int brow0 = b * TT;
        for (int idx = tid; idx < TT * 13; idx += 256) {
            int row = idx / 13;
            int m = idx - row * 13;
            int j = 4 * m;
            const float* hrow = &h_all[row * 64];
            float ax = 0.f, ay = 0.f, az = 0.f, aw = 0.f;
#pragma unroll
            for (int u4 = 0; u4 < 16; ++u4) {
                float4 hv  = *(const float4*)&hrow[4 * u4];
                float4 w0  = *(const float4*)&w1s[(4 * u4 + 0) * 52 + j];
                float4 w1v = *(const float4*)&w1s[(4 * u4 + 1) * 52 + j];
                float4 w2  = *(const float4*)&w1s[(4 * u4 + 2) * 52 + j];
                float4 w3  = *(const float4*)&w1s[(4 * u4 + 3) * 52 + j];
                ax += hv.x * w0.x + hv.y * w1v.x + hv.z * w2.x + hv.w * w3.x;
                ay += hv.x * w0.y + hv.y * w1v.y + hv.z * w2.y + hv.w * w3.y;
                az += hv.x * w0.z + hv.y * w1v.z + hv.z * w2.z + hv.w * w3.z;
                aw += hv.x * w0.w + hv.y * w1v.w + hv.z * w2.w + hv.w * w3.w;
            }
            if (m == 12) { az = 0.f; aw = 0.f; }   // cols 50,51 = 0
            *(float4*)&G[(brow0 + row) * GROW + j] = make_float4(ax, ay, az, aw);
        }
    } else if (bid < 24) {
        // ---- XcT[j][p] = b1[j] + sum_k X[p][k]*W1[64+k][j] ----
        float* Xs  = smem;          // [128][65]
        float* W1T = smem + 8320;   // [50][128]
        const int p0 = (bid - 8) * 64;
        for (int idx = tid; idx < 6400; idx += 256) {
            int k = idx & 127, jj = idx >> 7;
            W1T[jj * 128 + k] = W1[(64 + k) * 50 + jj];
        }
#pragma unroll
        for (int r = 0; r < 8; ++r) {
            int flat = (tid + 256 * r) * 4;
            int i = flat >> 7;
            int k = flat & 127;
            int p = p0 + i;
            float4 v = make_float4(0.f, 0.f, 0.f, 0.f);
            if (p < PP) v = *(const float4*)&X[p * 128 + k];
            Xs[(k + 0) * 65 + i] = v.x;
            Xs[(k + 1) * 65 + i] = v.y;
            Xs[(k + 2) * 65 + i] = v.z;
            Xs[(k + 3) * 65 + i] = v.w;
        }
        __syncthreads();
        const int ploc = tid & 63;
        const int j0 = tid >> 6;
        float acc[13];
#pragma unroll
        for (int m = 0; m < 13; ++m) {
            int jj = j0 * 13 + m;
            acc[m] = (jj < 50) ? b1[jj] : 0.f;
        }
        for (int k4 = 0; k4 < 32; ++k4) {
            const int k = 4 * k4;
            float x0 = Xs[(k + 0) * 65 + ploc];
            float x1 = Xs[(k + 1) * 65 + ploc];
            float x2 = Xs[(k + 2) * 65 + ploc];
            float x3 = Xs[(k + 3) * 65 + ploc];
#pragma unroll
            for (int m = 0; m < 13; ++m) {
                int jj = j0 * 13 + m;
                if (jj < 50) {
                    float4 wv = *(const float4*)&W1T[jj * 128 + k];
                    acc[m] += x0 * wv.x + x1 * wv.y + x2 * wv.z + x3 * wv.w;
                }
            }
        }
        int p = p0 + ploc;
        if (p < PP) {
#pragma unroll
            for (int m = 0; m < 13; ++m) {
                int jj = j0 * 13 + m;
                if (jj < 50) XcT[jj * PP + p] = acc[m];
            }
        }
        for (int idx = tid; idx < 6 * 64; idx += 256) {
            int r = 50 + (idx >> 6);
            int pp = p0 + (idx & 63);
            if (pp < PP) XcT[r * PP + pp] = 0.f;
        }
    }

    gbar(&bar[1]);

    // ================= PHASE C: blocks 0..31 = zero-redundancy k4 suffix scan ==========
    if (bid < 32) {
        int* spid = (int*)smem;
        const int b = bid >> 2;
        const int p = (bid & 3) * 256 + tid;
        const bool valid = p < PP;
        const int pc = valid ? p : 0;

        if (tid < TT) spid[tid] = pro_id[b * TT + tid];

        float4 w2r[13];
#pragma unroll
        for (int jv = 0; jv < 12; ++jv) w2r[jv] = *(const float4*)&W2[4 * jv];
        w2r[12] = make_float4(W2[48], W2[49], 0.f, 0.f);
        const float b2v = b2[0];

        float V[NJ];
#pragma unroll
        for (int jj = 0; jj < NJ; ++jj) V[jj] = XcT[jj * PP + pc];
        __syncthreads();

        const float* cb = cos_X + pc;
        float a0 = cb[spid[99] * PP];
        float a1 = cb[spid[98] * PP];
        float a2 = cb[spid[97] * PP];
        float a3 = cb[spid[96] * PP];

        const float4* Gb = (const float4*)(G + b * TT * GROW);  // 14 float4 / row
        float4 Gn[13];
#pragma unroll
        for (int jv = 0; jv < 13; ++jv) Gn[jv] = Gb[99 * 14 + jv];

        float* outb = out + b * TT * PP + p;

        for (int s = TT - 1; s >= 0; --s) {
            float4 Gc[13];
#pragma unroll
            for (int jv = 0; jv < 13; ++jv) Gc[jv] = Gn[jv];
            int sn = (s > 0) ? s - 1 : 0;
#pragma unroll
            for (int jv = 0; jv < 13; ++jv) Gn[jv] = Gb[sn * 14 + jv];

            float a = a0; a0 = a1; a1 = a2; a2 = a3;
            int sp = (s >= 4) ? s - 4 : 0;
            a3 = cb[spid[sp] * PP];

            float acc = b2v;
#pragma unroll
            for (int jv = 0; jv < 13; ++jv) {
                float4 gv = Gc[jv];
                V[4 * jv + 0] += a * gv.x;
                V[4 * jv + 1] += a * gv.y;
                V[4 * jv + 2] += a * gv.z;
                V[4 * jv + 3] += a * gv.w;
                float4 wv = w2r[jv];
                acc += wv.x * fmaxf(V[4 * jv + 0], 0.f)
                     + wv.y * fmaxf(V[4 * jv + 1], 0.f)
                     + wv.z * fmaxf(V[4 * jv + 2], 0.f)
                     + wv.w * fmaxf(V[4 * jv + 3], 0.f);
            }
            if (valid) outb[s * PP] = acc;
        }
    }
}

extern "C" void kernel_launch(void* const* d_in, const int* in_sizes, int n_in,
                              void* d_out, int out_size, void* d_ws, size_t ws_size,
                              hipStream_t stream)
{
    const int* pro_id  = (const int*)d_in[0];
    const int* label   = (const int*)d_in[1];
    const float* X     = (const float*)d_in[3];
    const float* cos_X = (const float*)d_in[4];
    // d_in[5] trimatrix: structurally tril(ones) — suffix-sum semantics hardcoded
    const float* onehot = (const float*)d_in[6];
    const float* lk    = (const float*)d_in[7];
    const float* lr    = (const float*)d_in[8];
    const float* lb    = (const float*)d_in[9];
    const float* W1    = (const float*)d_in[10];
    const float* b1    = (const float*)d_in[11];
    const float* W2    = (const float*)d_in[12];
    const float* b2    = (const float*)d_in[13];

    float* ws  = (float*)d_ws;
    float* xk  = ws;            // 204800
    float* XcT = ws + 204800;   // 56000
    float* G   = ws + 260800;   // 44800
    int*   bar = (int*)(ws + 305600);  // 2 ints, zeroed below each call
    float* out = (float*)d_out;

    hipMemsetAsync(bar, 0, 2 * sizeof(int), stream);
    hipLaunchKernelGGL(fused, dim3(NBLK), dim3(256), 0, stream,
                       pro_id, label, X, cos_X, onehot, lk, lr, lb,
                       W1, b1, W2, b2, xk, XcT, G, out, bar);
}

// Round 16
// 205.753 us; speedup vs baseline: 1.2155x; 1.2155x over previous
//
#include <hip/hip_runtime.h>
#include <math.h>

#define TT 100
#define PP 1000
#define NJ 52      // padded j count (50 real)
#define GROW 56    // G row stride floats (224B, 16B aligned; 14 float4)

typedef _Float16 half2v __attribute__((ext_vector_type(2)));

__device__ __forceinline__ half2v as_h2(float f) {
    union { float x; half2v h; } u; u.x = f; return u.h;
}

// ws layout (floats):
//   xk : [800][256] at 0        (204800)
//   XcT: [56][1000] at 204800   (56000)
//   G  : [800][56]  at 260800   (44800)

// ---------------- K1: xk[bt][j] = bias[j] + sum_k xt[bt][k]*kern[k][j] -----------------
__global__ __launch_bounds__(256) void k1_xk(const int* __restrict__ pro_id,
    const int* __restrict__ label, const float* __restrict__ X,
    const float* __restrict__ onehot, const float* __restrict__ kern,
    const float* __restrict__ bias, float* __restrict__ xk)
{
    __shared__ __align__(16) float xt[2][256];
    const int j = threadIdx.x;
    const int r0 = blockIdx.x * 2;
#pragma unroll
    for (int r = 0; r < 2; ++r) {
        int pid = pro_id[r0 + r];
        int lab = label[r0 + r];
        xt[r][j] = X[pid * 128 + (j & 127)] * onehot[lab * 256 + j];
    }
    __syncthreads();
    float acc0 = bias[j], acc1 = acc0;
    float kc[8];
#pragma unroll
    for (int i = 0; i < 8; ++i) kc[i] = kern[i * 256 + j];
    for (int kg = 0; kg < 32; ++kg) {
        float kn[8];
        const int kgn = (kg < 31) ? kg + 1 : 31;
#pragma unroll
        for (int i = 0; i < 8; ++i) kn[i] = kern[(kgn * 8 + i) * 256 + j];
        const int k0 = kg * 8;
        float4 xa0 = *(const float4*)&xt[0][k0];
        float4 xa1 = *(const float4*)&xt[0][k0 + 4];
        float4 xb0 = *(const float4*)&xt[1][k0];
        float4 xb1 = *(const float4*)&xt[1][k0 + 4];
        acc0 += xa0.x * kc[0] + xa0.y * kc[1] + xa0.z * kc[2] + xa0.w * kc[3]
              + xa1.x * kc[4] + xa1.y * kc[5] + xa1.z * kc[6] + xa1.w * kc[7];
        acc1 += xb0.x * kc[0] + xb0.y * kc[1] + xb0.z * kc[2] + xb0.w * kc[3]
              + xb1.x * kc[4] + xb1.y * kc[5] + xb1.z * kc[6] + xb1.w * kc[7];
#pragma unroll
        for (int i = 0; i < 8; ++i) kc[i] = kn[i];
    }
    xk[(r0 + 0) * 256 + j] = acc0;
    xk[(r0 + 1) * 256 + j] = acc1;
}

// ---------------- MID: blocks 0..7 = LSTM v7 (1 batch), blocks 8..23 = XcT -------------
__global__ __launch_bounds__(256, 1) void mid(const float* __restrict__ xk,
    const float* __restrict__ rec, const float* __restrict__ W1,
    const float* __restrict__ X, const float* __restrict__ b1,
    float* __restrict__ G, float* __restrict__ XcT)
{
    __shared__ __align__(16) float smem[14720];  // 58.9 KB union
    const int tid = threadIdx.x;

    if (blockIdx.x < 8) {
        float* h_all  = smem;            // [100][64] f32 = 25600 B
        float* hwork  = smem + 6400;     // [64] f16 = 128 B
        float* w1s    = smem + 6432;     // [64][52] = 13312 B
        const int b = blockIdx.x;

        if (tid >= 64) {                 // waves 1..3 stage w1s
            for (int idx = tid - 64; idx < 3200; idx += 192) {
                int u2 = idx / 50, jj = idx - u2 * 50;
                w1s[u2 * 52 + jj] = W1[idx];
            }
        }

        if (tid < 64) {                  // wave 0: the whole recurrence
            const int u = tid;
            half2v rp[4][32];
#pragma unroll
            for (int m = 0; m < 32; ++m) {
#pragma unroll
                for (int g2 = 0; g2 < 4; ++g2) {
                    float r0v = rec[(2 * m) * 256 + g2 * 64 + u];
                    float r1v = rec[(2 * m + 1) * 256 + g2 * 64 + u];
                    half2v pv; pv.x = (_Float16)r0v; pv.y = (_Float16)r1v;
                    rp[g2][m] = pv;
                }
            }
            ((_Float16*)hwork)[u] = (_Float16)0.f;   // h(-1) = 0

            const float* xkb = xk + b * TT * 256;
            float xi0 = xkb[u],             xf0 = xkb[64 + u],
                  xg0 = xkb[128 + u],       xo0 = xkb[192 + u];
            float xi1 = xkb[256 + u],       xf1 = xkb[256 + 64 + u],
                  xg1 = xkb[256 + 128 + u], xo1 = xkb[256 + 192 + u];
            float xi2 = xkb[512 + u],       xf2 = xkb[512 + 64 + u],
                  xg2 = xkb[512 + 128 + u], xo2 = xkb[512 + 192 + u];
            float c = 0.f;

            for (int t = 0; t < TT; ++t) {
                float zi = xi0, zf = xf0, zg = xg0, zo = xo0;
                xi0 = xi1; xf0 = xf1; xg0 = xg1; xo0 = xo1;
                xi1 = xi2; xf1 = xf2; xg1 = xg2; xo1 = xo2;
                int tn = (t + 3 < TT) ? t + 3 : TT - 1;
                const float* xp = xkb + tn * 256;
                xi2 = xp[u]; xf2 = xp[64 + u]; xg2 = xp[128 + u]; xo2 = xp[192 + u];

                const float4* hw4 = (const float4*)hwork;
#pragma unroll
                for (int ch = 0; ch < 8; ++ch) {
                    float4 hv = hw4[ch];
                    half2v p0 = as_h2(hv.x), p1 = as_h2(hv.y),
                           p2 = as_h2(hv.z), p3 = as_h2(hv.w);
                    zi = __builtin_amdgcn_fdot2(p0, rp[0][ch * 4 + 0], zi, false);
                    zf = __builtin_amdgcn_fdot2(p0, rp[1][ch * 4 + 0], zf, false);
                    zg = __builtin_amdgcn_fdot2(p0, rp[2][ch * 4 + 0], zg, false);
                    zo = __builtin_amdgcn_fdot2(p0, rp[3][ch * 4 + 0], zo, false);
                    zi = __builtin_amdgcn_fdot2(p1, rp[0][ch * 4 + 1], zi, false);
                    zf = __builtin_amdgcn_fdot2(p1, rp[1][ch * 4 + 1], zf, false);
                    zg = __builtin_amdgcn_fdot2(p1, rp[2][ch * 4 + 1], zg, false);
                    zo = __builtin_amdgcn_fdot2(p1, rp[3][ch * 4 + 1], zo, false);
                    zi = __builtin_amdgcn_fdot2(p2, rp[0][ch * 4 + 2], zi, false);
                    zf = __builtin_amdgcn_fdot2(p2, rp[1][ch * 4 + 2], zf, false);
                    zg = __builtin_amdgcn_fdot2(p2, rp[2][ch * 4 + 2], zg, false);
                    zo = __builtin_amdgcn_fdot2(p2, rp[3][ch * 4 + 2], zo, false);
                    zi = __builtin_amdgcn_fdot2(p3, rp[0][ch * 4 + 3], zi, false);
                    zf = __builtin_amdgcn_fdot2(p3, rp[1][ch * 4 + 3], zf, false);
                    zg = __builtin_amdgcn_fdot2(p3, rp[2][ch * 4 + 3], zg, false);
                    zo = __builtin_amdgcn_fdot2(p3, rp[3][ch * 4 + 3], zo, false);
                }
                float gi = 1.f / (1.f + __expf(-zi));
                float gf = 1.f / (1.f + __expf(-zf));
                float gg = 2.f / (1.f + __expf(-2.f * zg)) - 1.f;
                float go = 1.f / (1.f + __expf(-zo));
                c = gf * c + gi * gg;
                float h = go * (2.f / (1.f + __expf(-2.f * c)) - 1.f);
                h_all[t * 64 + u] = h;                 // f32 history for tail
                ((_Float16*)hwork)[u] = (_Float16)h;   // f16 row for next step
            }
        }
        __syncthreads();

        // ---- G tail (all 256 threads): G[b*100+row][j] = h(row) . W1[:,j] ----
        const int brow0 = b * TT;
        for (int idx = tid; idx < TT * 13; idx += 256) {
            int row = idx / 13;
            int m = idx - row * 13;
            int j = 4 * m;
            const float* hrow = &h_all[row * 64];
            float ax = 0.f, ay = 0.f, az = 0.f, aw = 0.f;
#pragma unroll
            for (int u4 = 0; u4 < 16; ++u4) {
                float4 hv  = *(const float4*)&hrow[4 * u4];
                float4 w0  = *(const float4*)&w1s[(4 * u4 + 0) * 52 + j];
                float4 w1v = *(const float4*)&w1s[(4 * u4 + 1) * 52 + j];
                float4 w2  = *(const float4*)&w1s[(4 * u4 + 2) * 52 + j];
                float4 w3  = *(const float4*)&w1s[(4 * u4 + 3) * 52 + j];
                ax += hv.x * w0.x + hv.y * w1v.x + hv.z * w2.x + hv.w * w3.x;
                ay += hv.x * w0.y + hv.y * w1v.y + hv.z * w2.y + hv.w * w3.y;
                az += hv.x * w0.z + hv.y * w1v.z + hv.z * w2.z + hv.w * w3.z;
                aw += hv.x * w0.w + hv.y * w1v.w + hv.z * w2.w + hv.w * w3.w;
            }
            if (m == 12) { az = 0.f; aw = 0.f; }   // cols 50,51 = 0
            *(float4*)&G[(brow0 + row) * GROW + j] = make_float4(ax, ay, az, aw);
        }
    } else {
        // ---- XcT[j][p] = b1[j] + sum_k X[p][k]*W1[64+k][j] ----
        float* Xs  = smem;          // [128][65]
        float* W1T = smem + 8320;   // [50][128]
        const int p0 = (blockIdx.x - 8) * 64;
        for (int idx = tid; idx < 6400; idx += 256) {
            int k = idx & 127, jj = idx >> 7;
            W1T[jj * 128 + k] = W1[(64 + k) * 50 + jj];
        }
#pragma unroll
        for (int r = 0; r < 8; ++r) {
            int flat = (tid + 256 * r) * 4;
            int i = flat >> 7;
            int k = flat & 127;
            int p = p0 + i;
            float4 v = make_float4(0.f, 0.f, 0.f, 0.f);
            if (p < PP) v = *(const float4*)&X[p * 128 + k];
            Xs[(k + 0) * 65 + i] = v.x;
            Xs[(k + 1) * 65 + i] = v.y;
            Xs[(k + 2) * 65 + i] = v.z;
            Xs[(k + 3) * 65 + i] = v.w;
        }
        __syncthreads();
        const int ploc = tid & 63;
        const int j0 = tid >> 6;
        float acc[13];
#pragma unroll
        for (int m = 0; m < 13; ++m) {
            int jj = j0 * 13 + m;
            acc[m] = (jj < 50) ? b1[jj] : 0.f;
        }
        for (int k4 = 0; k4 < 32; ++k4) {
            const int k = 4 * k4;
            float x0 = Xs[(k + 0) * 65 + ploc];
            float x1 = Xs[(k + 1) * 65 + ploc];
            float x2 = Xs[(k + 2) * 65 + ploc];
            float x3 = Xs[(k + 3) * 65 + ploc];
#pragma unroll
            for (int m = 0; m < 13; ++m) {
                int jj = j0 * 13 + m;
                if (jj < 50) {
                    float4 wv = *(const float4*)&W1T[jj * 128 + k];
                    acc[m] += x0 * wv.x + x1 * wv.y + x2 * wv.z + x3 * wv.w;
                }
            }
        }
        int p = p0 + ploc;
        if (p < PP) {
#pragma unroll
            for (int m = 0; m < 13; ++m) {
                int jj = j0 * 13 + m;
                if (jj < 50) XcT[jj * PP + p] = acc[m];
            }
        }
        for (int idx = tid; idx < 6 * 64; idx += 256) {
            int r = 50 + (idx >> 6);
            int pp = p0 + (idx & 63);
            if (pp < PP) XcT[r * PP + pp] = 0.f;
        }
    }
}

// ---------------- K4 v5: zero-redundancy scan, FULL register budget ---------------------
// __launch_bounds__(256, 1): V[52]+Gc[52]+Gn[52]+w2r[26]+temps ~ 200 VGPRs must
// all live in registers. R12-R15's k4 variants spilled V/G to scratch (fused
// VGPR=136 < needs; scratch hits L2 so HBM counters looked clean) -- that was
// the hidden ~60-80us. 32 blocks = 1 block/CU, 4 waves; G rows wave-uniform
// global loads, 1-row prefetch; out stores coalesced.
__global__ __launch_bounds__(256, 1) void k4_main(const int* __restrict__ pro_id,
    const float* __restrict__ cos_X, const float* __restrict__ XcT,
    const float* __restrict__ G, const float* __restrict__ W2,
    const float* __restrict__ b2, float* __restrict__ out)
{
    __shared__ int spid[TT];
    const int b = blockIdx.y;
    const int p = blockIdx.x * 256 + threadIdx.x;
    const bool valid = p < PP;
    const int pc = valid ? p : 0;
    const int tid = threadIdx.x;

    if (tid < TT) spid[tid] = pro_id[b * TT + tid];

    float4 w2r[13];
#pragma unroll
    for (int jv = 0; jv < 12; ++jv) w2r[jv] = *(const float4*)&W2[4 * jv];
    w2r[12] = make_float4(W2[48], W2[49], 0.f, 0.f);
    const float b2v = b2[0];

    float V[NJ];
#pragma unroll
    for (int jj = 0; jj < NJ; ++jj) V[jj] = XcT[jj * PP + pc];
    __syncthreads();

    const float* cb = cos_X + pc;
    float a0 = cb[spid[99] * PP];
    float a1 = cb[spid[98] * PP];
    float a2 = cb[spid[97] * PP];
    float a3 = cb[spid[96] * PP];

    const float4* Gb = (const float4*)(G + b * TT * GROW);  // 14 float4 / row
    float4 Gn[13];
#pragma unroll
    for (int jv = 0; jv < 13; ++jv) Gn[jv] = Gb[99 * 14 + jv];  // prefetch s=99

    float* outb = out + b * TT * PP + p;

    for (int s = TT - 1; s >= 0; --s) {
        float4 Gc[13];
#pragma unroll
        for (int jv = 0; jv < 13; ++jv) Gc[jv] = Gn[jv];
        int sn = (s > 0) ? s - 1 : 0;
#pragma unroll
        for (int jv = 0; jv < 13; ++jv) Gn[jv] = Gb[sn * 14 + jv];  // in flight

        float a = a0; a0 = a1; a1 = a2; a2 = a3;
        int sp = (s >= 4) ? s - 4 : 0;
        a3 = cb[spid[sp] * PP];

        float acc = b2v;
#pragma unroll
        for (int jv = 0; jv < 13; ++jv) {
            float4 gv = Gc[jv];
            V[4 * jv + 0] += a * gv.x;
            V[4 * jv + 1] += a * gv.y;
            V[4 * jv + 2] += a * gv.z;
            V[4 * jv + 3] += a * gv.w;
            float4 wv = w2r[jv];
            acc += wv.x * fmaxf(V[4 * jv + 0], 0.f)
                 + wv.y * fmaxf(V[4 * jv + 1], 0.f)
                 + wv.z * fmaxf(V[4 * jv + 2], 0.f)
                 + wv.w * fmaxf(V[4 * jv + 3], 0.f);
        }
        if (valid) outb[s * PP] = acc;
    }
}

extern "C" void kernel_launch(void* const* d_in, const int* in_sizes, int n_in,
                              void* d_out, int out_size, void* d_ws, size_t ws_size,
                              hipStream_t stream)
{
    const int* pro_id  = (const int*)d_in[0];
    const int* label   = (const int*)d_in[1];
    const float* X     = (const float*)d_in[3];
    const float* cos_X = (const float*)d_in[4];
    // d_in[5] trimatrix: structurally tril(ones) — suffix-sum semantics hardcoded
    const float* onehot = (const float*)d_in[6];
    const float* lk    = (const float*)d_in[7];
    const float* lr    = (const float*)d_in[8];
    const float* lb    = (const float*)d_in[9];
    const float* W1    = (const float*)d_in[10];
    const float* b1    = (const float*)d_in[11];
    const float* W2    = (const float*)d_in[12];
    const float* b2    = (const float*)d_in[13];

    float* ws  = (float*)d_ws;
    float* xk  = ws;            // 204800
    float* XcT = ws + 204800;   // 56000
    float* G   = ws + 260800;   // 44800
    float* out = (float*)d_out;

    hipLaunchKernelGGL(k1_xk,  dim3(400),    dim3(256), 0, stream,
                       pro_id, label, X, onehot, lk, lb, xk);
    hipLaunchKernelGGL(mid,    dim3(24),     dim3(256), 0, stream,
                       xk, lr, W1, X, b1, G, XcT);
    hipLaunchKernelGGL(k4_main,dim3(4, 8),   dim3(256), 0, stream,
                       pro_id, cos_X, XcT, G, W2, b2, out);
}